// Round 4
// baseline (1042.954 us; speedup 1.0000x reference)
//
#include <hip/hip_runtime.h>
#include <cstddef>
#include <cstdint>

// Problem constants (B,T,D,H) = (64,512,2048,128)
#define BB 64
#define TT 512
#define DD 2048
#define HH 128
#define M1 (BB*TT)   // 32768 rows for both GEMMs

typedef __attribute__((ext_vector_type(8))) _Float16 f16x8;
typedef __attribute__((ext_vector_type(4))) float f32x4;
typedef __attribute__((ext_vector_type(2))) _Float16 h2f;

__device__ __forceinline__ float tanh_fast(float x) {
    float e2x = __builtin_amdgcn_exp2f(x * 2.885390081777927f);
    return 1.0f - 2.0f * __builtin_amdgcn_rcpf(e2x + 1.0f);
}
__device__ __forceinline__ h2f bch2(unsigned u) { return __builtin_bit_cast(h2f, u); }

// ---------------------------------------------------------------------------
// prep: fp32 -> fp16 convert (for W_ih1, W_ih2). n divisible by 1024.
// ---------------------------------------------------------------------------
__global__ __launch_bounds__(256) void prep_f16_kernel(
    const float* __restrict__ W, _Float16* __restrict__ Wf)
{
    const int i = (blockIdx.x * 256 + threadIdx.x) * 4;
    float4 w = *(const float4*)(W + i);
    f16x8 dummy;
    _Float16 o0 = (_Float16)w.x, o1 = (_Float16)w.y;
    _Float16 o2 = (_Float16)w.z, o3 = (_Float16)w.w;
    ushort4 ov;
    ov.x = __builtin_bit_cast(unsigned short, o0);
    ov.y = __builtin_bit_cast(unsigned short, o1);
    ov.z = __builtin_bit_cast(unsigned short, o2);
    ov.w = __builtin_bit_cast(unsigned short, o3);
    *(ushort4*)((unsigned short*)Wf + i) = ov;
    (void)dummy;
}

// ---------------------------------------------------------------------------
// fp16 MFMA GEMM: out[m][n] = sum_k A[m][k]*W[n][k] + bia[n] + bib[n]
// 16x16x32_f16, BM=64 (4 waves x 16 rows), N=128 (8 n-tiles), BK=32.
// CONVA: A is fp32, converted to f16 in-kernel. !CONVA: A already f16.
// Verified layouts (R2 passed): A[m=lane&15][k=(lane>>4)*8+j];
// C/D col=lane&15, row=(lane>>4)*4+r.
// ---------------------------------------------------------------------------
template<int K, bool CONVA>
__global__ __launch_bounds__(256) void gemm_f16_mfma(
    const void* __restrict__ Araw, const _Float16* __restrict__ Wf,
    const float* __restrict__ bia, const float* __restrict__ bib,
    float* __restrict__ out)
{
    constexpr int BK = 32, NK = K / BK;
    __shared__ __align__(16) _Float16 Af[64 * 40];    // stride 40: pad 8
    __shared__ __align__(16) _Float16 Ws[128 * 40];

    const int tid = threadIdx.x, wave = tid >> 6, lane = tid & 63;
    const size_t m0 = (size_t)blockIdx.x * 64;
    const int ar = tid >> 2, ak = (tid & 3) * 8;      // A: row, k0 (8 f16)
    const int wr = tid >> 1, wk = (tid & 1) * 16;     // W: row, k0 (16 f16)
    const _Float16* Wp = Wf + (size_t)wr * K + wk;
    const int frow = lane & 15, fko = (lane >> 4) * 8;

    f32x4 acc[8];
#pragma unroll
    for (int i = 0; i < 8; i++) acc[i] = (f32x4){0.f, 0.f, 0.f, 0.f};

    for (int kt = 0; kt < NK; ++kt) {
        f16x8 astage;
        if (CONVA) {
            const float* Ap = (const float*)Araw + (m0 + ar) * (size_t)K + kt * BK + ak;
            float4 a0 = *(const float4*)Ap;
            float4 a1 = *(const float4*)(Ap + 4);
            astage[0] = (_Float16)a0.x; astage[1] = (_Float16)a0.y;
            astage[2] = (_Float16)a0.z; astage[3] = (_Float16)a0.w;
            astage[4] = (_Float16)a1.x; astage[5] = (_Float16)a1.y;
            astage[6] = (_Float16)a1.z; astage[7] = (_Float16)a1.w;
        } else {
            const _Float16* Ap = (const _Float16*)Araw + (m0 + ar) * (size_t)K + kt * BK + ak;
            astage = *(const f16x8*)Ap;
        }
        f16x8 w0 = *(const f16x8*)(Wp + kt * BK);
        f16x8 w1 = *(const f16x8*)(Wp + kt * BK + 8);
        __syncthreads();   // previous iter's fragment reads complete
        *(f16x8*)&Af[ar * 40 + ak] = astage;
        *(f16x8*)&Ws[wr * 40 + wk] = w0;
        *(f16x8*)&Ws[wr * 40 + wk + 8] = w1;
        __syncthreads();
        f16x8 fA = *(const f16x8*)&Af[(wave * 16 + frow) * 40 + fko];
#pragma unroll
        for (int nt = 0; nt < 8; ++nt) {
            f16x8 fW = *(const f16x8*)&Ws[(nt * 16 + frow) * 40 + fko];
            acc[nt] = __builtin_amdgcn_mfma_f32_16x16x32_f16(fA, fW, acc[nt], 0, 0, 0);
        }
    }
    const int rbase = (lane >> 4) * 4;
#pragma unroll
    for (int nt = 0; nt < 8; ++nt) {
        const int col = nt * 16 + frow;
        const float bv = bia[col] + bib[col];
#pragma unroll
        for (int r = 0; r < 4; r++)
            out[(m0 + wave * 16 + rbase + r) * HH + col] = acc[nt][r] + bv;
    }
}

// ---------------------------------------------------------------------------
// Scan v4: 2 waves per batch, lane owns output j = tid. FULL K=128 per lane:
// 16 x (b128 broadcast read + 4 fdot2), 8 independent accumulator chains.
// h double-buffered in 2x256B LDS, ONE barrier per step. pre prefetched
// 8 steps deep (hides ~900cyc HBM latency). STORE: write h (fp16) to hout.
// ---------------------------------------------------------------------------
template<bool STORE>
__global__ __launch_bounds__(128) void rnn_scan2w(
    const float* __restrict__ pre,    // [64][512][128] fp32
    const float* __restrict__ Whh,    // [128][128] fp32
    _Float16* __restrict__ hout,      // [64][512][128] f16 (iff STORE)
    const float* __restrict__ Wfc, const float* __restrict__ bfc,
    float* __restrict__ outv)         // [64]
{
    __shared__ __align__(16) _Float16 hbuf[2][HH];   // 256 B each
    __shared__ float wsum[2];
    const int tid = threadIdx.x;        // 0..127
    const int w = tid >> 6, lane = tid & 63;
    const int j = tid;                  // output index
    const int b = blockIdx.x;

    // W_hh row j as 64 packed f16 pairs (64 VGPRs): Wr[q] = (w[2q], w[2q+1])
    h2f Wr[64];
    {
        const float* wp = Whh + (size_t)j * HH;
#pragma unroll
        for (int q = 0; q < 32; q++) {
            float4 wv = *(const float4*)(wp + q * 4);
            Wr[2 * q]     = h2f{(_Float16)wv.x, (_Float16)wv.y};
            Wr[2 * q + 1] = h2f{(_Float16)wv.z, (_Float16)wv.w};
        }
    }
    if (tid < 64) ((unsigned*)hbuf[0])[tid] = 0u;   // h(=0) for t=0
    __syncthreads();

    const float* pb = pre + (size_t)b * TT * HH;
    _Float16* hob = hout + (size_t)b * TT * HH;
    float fc = 0.f;

    constexpr int PF = 8;               // prefetch depth (8 outstanding loads)
    float pf[PF];
#pragma unroll
    for (int i = 0; i < PF; i++) pf[i] = pb[(size_t)i * HH + j];

    for (int tb = 0; tb < TT; tb += PF) {
        const bool more = (tb + PF < TT);
#pragma unroll
        for (int u = 0; u < PF; u++) {
            const int t = tb + u;
            const float p = pf[u];
            if (more) pf[u] = pb[(size_t)(t + PF) * HH + j];  // issue early

            const _Float16* hr = hbuf[t & 1];
            _Float16* hw = hbuf[(t + 1) & 1];

            float a[8];
#pragma unroll
            for (int q = 0; q < 8; q++) a[q] = 0.f;
#pragma unroll
            for (int q = 0; q < 16; q++) {           // FULL K=128: 16 x uint4
                uint4 hv = *(const uint4*)&hr[q * 8];
                float aq = a[q % 8];
                aq = __builtin_amdgcn_fdot2(Wr[4 * q + 0], bch2(hv.x), aq, false);
                aq = __builtin_amdgcn_fdot2(Wr[4 * q + 1], bch2(hv.y), aq, false);
                aq = __builtin_amdgcn_fdot2(Wr[4 * q + 2], bch2(hv.z), aq, false);
                aq = __builtin_amdgcn_fdot2(Wr[4 * q + 3], bch2(hv.w), aq, false);
                a[q % 8] = aq;
            }
            const float s = (((a[0] + a[1]) + (a[2] + a[3])) +
                             ((a[4] + a[5]) + (a[6] + a[7]))) + p;
            const float h = tanh_fast(s);
            const _Float16 hh = (_Float16)h;
            hw[j] = hh;
            if (STORE) hob[(size_t)t * HH + j] = hh;
            if (t == TT - 1) fc = h * Wfc[j];
            __syncthreads();
        }
    }

    if (!STORE) {
#pragma unroll
        for (int off = 1; off < 64; off <<= 1) fc += __shfl_xor(fc, off);
        if (lane == 0) wsum[w] = fc;
        __syncthreads();
        if (tid == 0) outv[b] = wsum[0] + wsum[1] + bfc[0];
    }
}

// ---------------------------------------------------------------------------
extern "C" void kernel_launch(void* const* d_in, const int* in_sizes, int n_in,
                              void* d_out, int out_size, void* d_ws, size_t ws_size,
                              hipStream_t stream) {
    const float* x    = (const float*)d_in[0];
    const float* Wih1 = (const float*)d_in[1];
    const float* Whh1 = (const float*)d_in[2];
    const float* bih1 = (const float*)d_in[3];
    const float* bhh1 = (const float*)d_in[4];
    const float* Wih2 = (const float*)d_in[5];
    const float* Whh2 = (const float*)d_in[6];
    const float* bih2 = (const float*)d_in[7];
    const float* bhh2 = (const float*)d_in[8];
    const float* Wfc  = (const float*)d_in[9];
    const float* bfc  = (const float*)d_in[10];
    float* out = (float*)d_out;

    // workspace layout (non-overlapping lifetimes checked):
    //   [0,16M)      preA  fp32 [M1][128]  (pre1, later pre2)
    //   [16M,24M)    h1b   f16  [M1][128]
    //   [24M,24.5M)  W1f   f16  [128][2048]
    //   [24.5M,..)   W2f   f16  [128][128]
    char* wsp = (char*)d_ws;
    float*     preA = (float*)wsp;
    _Float16*  h1b  = (_Float16*)(wsp + (size_t)16 * 1024 * 1024);
    _Float16*  W1f  = (_Float16*)(wsp + (size_t)24 * 1024 * 1024);
    _Float16*  W2f  = (_Float16*)(wsp + (size_t)24 * 1024 * 1024 + 512 * 1024);

    prep_f16_kernel<<<dim3(HH * DD / 1024), dim3(256), 0, stream>>>(Wih1, W1f);
    prep_f16_kernel<<<dim3(HH * HH / 1024), dim3(256), 0, stream>>>(Wih2, W2f);
    // layer 1: pre1 = x @ W_ih1^T + b  (fp16 MFMA, in-kernel x conversion)
    gemm_f16_mfma<DD, true><<<dim3(M1 / 64), dim3(256), 0, stream>>>(
        x, W1f, bih1, bhh1, preA);
    // layer 1 scan -> h1 (fp16)
    rnn_scan2w<true><<<dim3(BB), dim3(128), 0, stream>>>(
        preA, Whh1, h1b, Wfc, bfc, out);
    // layer 2: pre2 = h1 @ W_ih2^T + b  (fp16 MFMA, A already fp16)
    gemm_f16_mfma<HH, false><<<dim3(M1 / 64), dim3(256), 0, stream>>>(
        h1b, W2f, bih2, bhh2, preA);
    // layer 2 scan + fused FC -> out[64]
    rnn_scan2w<false><<<dim3(BB), dim3(128), 0, stream>>>(
        preA, Whh2, h1b, Wfc, bfc, out);
}

// Round 5
// 1039.709 us; speedup vs baseline: 1.0031x; 1.0031x over previous
//
#include <hip/hip_runtime.h>
#include <cstddef>
#include <cstdint>

// Problem constants (B,T,D,H) = (64,512,2048,128)
#define BB 64
#define TT 512
#define DD 2048
#define HH 128
#define M1 (BB*TT)   // 32768 rows for both GEMMs

typedef __attribute__((ext_vector_type(8))) _Float16 f16x8;
typedef __attribute__((ext_vector_type(4))) float f32x4;
typedef __attribute__((ext_vector_type(2))) _Float16 h2f;

__device__ __forceinline__ float tanh_fast(float x) {
    float e2x = __builtin_amdgcn_exp2f(x * 2.885390081777927f);
    return 1.0f - 2.0f * __builtin_amdgcn_rcpf(e2x + 1.0f);
}
__device__ __forceinline__ h2f bch2(unsigned u) { return __builtin_bit_cast(h2f, u); }

// ---------------------------------------------------------------------------
// prep: fp32 -> fp16 convert (for W_ih1, W_ih2). n divisible by 1024.
// ---------------------------------------------------------------------------
__global__ __launch_bounds__(256) void prep_f16_kernel(
    const float* __restrict__ W, _Float16* __restrict__ Wf)
{
    const int i = (blockIdx.x * 256 + threadIdx.x) * 4;
    float4 w = *(const float4*)(W + i);
    _Float16 o0 = (_Float16)w.x, o1 = (_Float16)w.y;
    _Float16 o2 = (_Float16)w.z, o3 = (_Float16)w.w;
    ushort4 ov;
    ov.x = __builtin_bit_cast(unsigned short, o0);
    ov.y = __builtin_bit_cast(unsigned short, o1);
    ov.z = __builtin_bit_cast(unsigned short, o2);
    ov.w = __builtin_bit_cast(unsigned short, o3);
    *(ushort4*)((unsigned short*)Wf + i) = ov;
}

// ---------------------------------------------------------------------------
// fp16 MFMA GEMM: out[m][n] = sum_k A[m][k]*W[n][k] + bia[n] + bib[n]
// 16x16x32_f16, BM=64 (4 waves x 16 rows), N=128 (8 n-tiles), BK=32.
// CONVA: A is fp32, converted to f16 in-kernel. !CONVA: A already f16.
// ---------------------------------------------------------------------------
template<int K, bool CONVA>
__global__ __launch_bounds__(256) void gemm_f16_mfma(
    const void* __restrict__ Araw, const _Float16* __restrict__ Wf,
    const float* __restrict__ bia, const float* __restrict__ bib,
    float* __restrict__ out)
{
    constexpr int BK = 32, NK = K / BK;
    __shared__ __align__(16) _Float16 Af[64 * 40];    // stride 40: pad 8
    __shared__ __align__(16) _Float16 Ws[128 * 40];

    const int tid = threadIdx.x, wave = tid >> 6, lane = tid & 63;
    const size_t m0 = (size_t)blockIdx.x * 64;
    const int ar = tid >> 2, ak = (tid & 3) * 8;      // A: row, k0 (8 f16)
    const int wr = tid >> 1, wk = (tid & 1) * 16;     // W: row, k0 (16 f16)
    const _Float16* Wp = Wf + (size_t)wr * K + wk;
    const int frow = lane & 15, fko = (lane >> 4) * 8;

    f32x4 acc[8];
#pragma unroll
    for (int i = 0; i < 8; i++) acc[i] = (f32x4){0.f, 0.f, 0.f, 0.f};

    for (int kt = 0; kt < NK; ++kt) {
        f16x8 astage;
        if (CONVA) {
            const float* Ap = (const float*)Araw + (m0 + ar) * (size_t)K + kt * BK + ak;
            float4 a0 = *(const float4*)Ap;
            float4 a1 = *(const float4*)(Ap + 4);
            astage[0] = (_Float16)a0.x; astage[1] = (_Float16)a0.y;
            astage[2] = (_Float16)a0.z; astage[3] = (_Float16)a0.w;
            astage[4] = (_Float16)a1.x; astage[5] = (_Float16)a1.y;
            astage[6] = (_Float16)a1.z; astage[7] = (_Float16)a1.w;
        } else {
            const _Float16* Ap = (const _Float16*)Araw + (m0 + ar) * (size_t)K + kt * BK + ak;
            astage = *(const f16x8*)Ap;
        }
        f16x8 w0 = *(const f16x8*)(Wp + kt * BK);
        f16x8 w1 = *(const f16x8*)(Wp + kt * BK + 8);
        __syncthreads();   // previous iter's fragment reads complete
        *(f16x8*)&Af[ar * 40 + ak] = astage;
        *(f16x8*)&Ws[wr * 40 + wk] = w0;
        *(f16x8*)&Ws[wr * 40 + wk + 8] = w1;
        __syncthreads();
        f16x8 fA = *(const f16x8*)&Af[(wave * 16 + frow) * 40 + fko];
#pragma unroll
        for (int nt = 0; nt < 8; ++nt) {
            f16x8 fW = *(const f16x8*)&Ws[(nt * 16 + frow) * 40 + fko];
            acc[nt] = __builtin_amdgcn_mfma_f32_16x16x32_f16(fA, fW, acc[nt], 0, 0, 0);
        }
    }
    const int rbase = (lane >> 4) * 4;
#pragma unroll
    for (int nt = 0; nt < 8; ++nt) {
        const int col = nt * 16 + frow;
        const float bv = bia[col] + bib[col];
#pragma unroll
        for (int r = 0; r < 4; r++)
            out[(m0 + wave * 16 + rbase + r) * HH + col] = acc[nt][r] + bv;
    }
}

// ---------------------------------------------------------------------------
// Scan v5: identical structure to v4 but __launch_bounds__(128, 1) so the
// 64-VGPR weight array stays REGISTER-RESIDENT (v4 spilled to scratch at
// VGPR_Count=72 -> ~1000 cyc/step scratch reloads).
// 2 waves per batch, lane owns output j = tid, full K=128 per lane as
// 16 x (b128 broadcast + 4 fdot2); h double-buffered in LDS; 1 barrier/step;
// pre prefetched 8 deep.
// ---------------------------------------------------------------------------
template<bool STORE>
__global__ __launch_bounds__(128, 1) void rnn_scan2w(
    const float* __restrict__ pre,    // [64][512][128] fp32
    const float* __restrict__ Whh,    // [128][128] fp32
    _Float16* __restrict__ hout,      // [64][512][128] f16 (iff STORE)
    const float* __restrict__ Wfc, const float* __restrict__ bfc,
    float* __restrict__ outv)         // [64]
{
    __shared__ __align__(16) _Float16 hbuf[2][HH];   // 256 B each
    __shared__ float wsum[2];
    const int tid = threadIdx.x;        // 0..127
    const int w = tid >> 6, lane = tid & 63;
    const int j = tid;                  // output index
    const int b = blockIdx.x;

    // W_hh row j as 64 packed f16 pairs (64 VGPRs): Wr[q] = (w[2q], w[2q+1])
    h2f Wr[64];
    {
        const float* wp = Whh + (size_t)j * HH;
#pragma unroll
        for (int q = 0; q < 32; q++) {
            float4 wv = *(const float4*)(wp + q * 4);
            Wr[2 * q]     = h2f{(_Float16)wv.x, (_Float16)wv.y};
            Wr[2 * q + 1] = h2f{(_Float16)wv.z, (_Float16)wv.w};
        }
    }
    if (tid < 64) ((unsigned*)hbuf[0])[tid] = 0u;   // h(=0) for t=0
    __syncthreads();

    const float* pb = pre + (size_t)b * TT * HH;
    _Float16* hob = hout + (size_t)b * TT * HH;
    float fc = 0.f;

    constexpr int PF = 8;               // prefetch depth (8 outstanding loads)
    float pf[PF];
#pragma unroll
    for (int i = 0; i < PF; i++) pf[i] = pb[(size_t)i * HH + j];

    for (int tb = 0; tb < TT; tb += PF) {
        const bool more = (tb + PF < TT);
#pragma unroll
        for (int u = 0; u < PF; u++) {
            const int t = tb + u;
            const float p = pf[u];
            if (more) pf[u] = pb[(size_t)(t + PF) * HH + j];  // issue early

            const _Float16* hr = hbuf[t & 1];
            _Float16* hw = hbuf[(t + 1) & 1];

            float a[8];
#pragma unroll
            for (int q = 0; q < 8; q++) a[q] = 0.f;
#pragma unroll
            for (int q = 0; q < 16; q++) {           // FULL K=128: 16 x uint4
                uint4 hv = *(const uint4*)&hr[q * 8];
                float aq = a[q % 8];
                aq = __builtin_amdgcn_fdot2(Wr[4 * q + 0], bch2(hv.x), aq, false);
                aq = __builtin_amdgcn_fdot2(Wr[4 * q + 1], bch2(hv.y), aq, false);
                aq = __builtin_amdgcn_fdot2(Wr[4 * q + 2], bch2(hv.z), aq, false);
                aq = __builtin_amdgcn_fdot2(Wr[4 * q + 3], bch2(hv.w), aq, false);
                a[q % 8] = aq;
            }
            const float s = (((a[0] + a[1]) + (a[2] + a[3])) +
                             ((a[4] + a[5]) + (a[6] + a[7]))) + p;
            const float h = tanh_fast(s);
            const _Float16 hh = (_Float16)h;
            hw[j] = hh;
            if (STORE) hob[(size_t)t * HH + j] = hh;
            if (t == TT - 1) fc = h * Wfc[j];
            __syncthreads();
        }
    }

    if (!STORE) {
#pragma unroll
        for (int off = 1; off < 64; off <<= 1) fc += __shfl_xor(fc, off);
        if (lane == 0) wsum[w] = fc;
        __syncthreads();
        if (tid == 0) outv[b] = wsum[0] + wsum[1] + bfc[0];
    }
}

// ---------------------------------------------------------------------------
extern "C" void kernel_launch(void* const* d_in, const int* in_sizes, int n_in,
                              void* d_out, int out_size, void* d_ws, size_t ws_size,
                              hipStream_t stream) {
    const float* x    = (const float*)d_in[0];
    const float* Wih1 = (const float*)d_in[1];
    const float* Whh1 = (const float*)d_in[2];
    const float* bih1 = (const float*)d_in[3];
    const float* bhh1 = (const float*)d_in[4];
    const float* Wih2 = (const float*)d_in[5];
    const float* Whh2 = (const float*)d_in[6];
    const float* bih2 = (const float*)d_in[7];
    const float* bhh2 = (const float*)d_in[8];
    const float* Wfc  = (const float*)d_in[9];
    const float* bfc  = (const float*)d_in[10];
    float* out = (float*)d_out;

    // workspace layout:
    //   [0,16M)      preA  fp32 [M1][128]  (pre1, later pre2)
    //   [16M,24M)    h1b   f16  [M1][128]
    //   [24M,24.5M)  W1f   f16  [128][2048]
    //   [24.5M,..)   W2f   f16  [128][128]
    char* wsp = (char*)d_ws;
    float*     preA = (float*)wsp;
    _Float16*  h1b  = (_Float16*)(wsp + (size_t)16 * 1024 * 1024);
    _Float16*  W1f  = (_Float16*)(wsp + (size_t)24 * 1024 * 1024);
    _Float16*  W2f  = (_Float16*)(wsp + (size_t)24 * 1024 * 1024 + 512 * 1024);

    prep_f16_kernel<<<dim3(HH * DD / 1024), dim3(256), 0, stream>>>(Wih1, W1f);
    prep_f16_kernel<<<dim3(HH * HH / 1024), dim3(256), 0, stream>>>(Wih2, W2f);
    gemm_f16_mfma<DD, true><<<dim3(M1 / 64), dim3(256), 0, stream>>>(
        x, W1f, bih1, bhh1, preA);
    rnn_scan2w<true><<<dim3(BB), dim3(128), 0, stream>>>(
        preA, Whh1, h1b, Wfc, bfc, out);
    gemm_f16_mfma<HH, false><<<dim3(M1 / 64), dim3(256), 0, stream>>>(
        h1b, W2f, bih2, bhh2, preA);
    rnn_scan2w<false><<<dim3(BB), dim3(128), 0, stream>>>(
        preA, Whh2, h1b, Wfc, bfc, out);
}